// Round 1
// baseline (2247.005 us; speedup 1.0000x reference)
//
#include <hip/hip_runtime.h>
#include <math.h>

typedef unsigned short u16;
typedef unsigned int u32;
typedef __bf16 bf16x8 __attribute__((ext_vector_type(8)));
typedef float f32x4 __attribute__((ext_vector_type(4)));
typedef u16 us8 __attribute__((ext_vector_type(8)));

#define TOKENS 1024
#define DIM 256
#define SEQ 512

// ---------- helpers ----------

__device__ __forceinline__ u16 f2bf(float f) {
  // round-to-nearest-even f32 -> bf16 (values are finite here)
  u32 x = __float_as_uint(f);
  x += 0x7fffu + ((x >> 16) & 1u);
  return (u16)(x >> 16);
}

// 256-thread block sum (4 waves of 64)
__device__ __forceinline__ float block_sum_256(float v) {
  __shared__ float red[4];
  int t = threadIdx.x, lane = t & 63, wid = t >> 6;
#pragma unroll
  for (int o = 32; o > 0; o >>= 1) v += __shfl_down(v, o, 64);
  __syncthreads();               // protect red from a previous call's readers
  if (lane == 0) red[wid] = v;
  __syncthreads();
  return red[0] + red[1] + red[2] + red[3];
}

// ---------- embedding + LN (eps 1e-12) ----------

__global__ void embed_ln(const int* __restrict__ ids, const float* __restrict__ wemb,
                         const float* __restrict__ tt, const float* __restrict__ pe,
                         const float* __restrict__ g, const float* __restrict__ bta,
                         float* __restrict__ out) {
  int row = blockIdx.x, t = threadIdx.x;
  int id = ids[row];
  // faithful quirk: token-type row 1 and positional row 1 for every position
  float v = wemb[(size_t)id * DIM + t] + tt[DIM + t] + pe[DIM + t];
  float mu = block_sum_256(v) * (1.0f / 256.0f);
  float d = v - mu;
  float var = block_sum_256(d * d) * (1.0f / 256.0f);
  out[(size_t)row * DIM + t] = d * rsqrtf(var + 1e-12f) * g[t] + bta[t];
}

// ---------- (optional gelu) + residual + LN ----------

__global__ void add_ln(const float* __restrict__ a, const float* __restrict__ res,
                       const float* __restrict__ g, const float* __restrict__ bta,
                       float* __restrict__ out, float eps, int dogelu) {
  int row = blockIdx.x, t = threadIdx.x;
  float v = a[(size_t)row * DIM + t];
  if (dogelu) v = 0.5f * v * (1.0f + erff(v * 0.70710678118654752f));
  if (res) v += res[(size_t)row * DIM + t];
  float mu = block_sum_256(v) * (1.0f / 256.0f);
  float d = v - mu;
  float var = block_sum_256(d * d) * (1.0f / 256.0f);
  float y = d * rsqrtf(var + eps);
  if (g) y = y * g[t] + bta[t];
  out[(size_t)row * DIM + t] = y;
}

// ---------- KAN input expansion: x -> [silu(x) | B-spline bases(x)] in bf16 ----------
// Xe layout per row n (ld = infeat*9): [0,infeat) = silu(x_i); [infeat + i*8 + c] = basis c of x_i.

__global__ void kan_expand(const float* __restrict__ X, u16* __restrict__ Xe,
                           int shift, int dorelu) {
  int idx = blockIdx.x * 256 + threadIdx.x;
  int infeat = 1 << shift;
  int n = idx >> shift, i = idx & (infeat - 1);
  float x = X[idx];
  if (dorelu) x = fmaxf(x, 0.0f);
  float sig = 1.0f / (1.0f + expf(-x));
  float si = x * sig;
  // Cox-de Boor, uniform extended grid g[j] = (j-3)*0.4f - 1.0f, f32-faithful
  float bs[11];
#pragma unroll
  for (int j = 0; j < 11; j++) {
    float gj  = (float)(j - 3) * 0.4f - 1.0f;
    float gj1 = (float)(j - 2) * 0.4f - 1.0f;
    bs[j] = (x >= gj && x < gj1) ? 1.0f : 0.0f;
  }
#pragma unroll
  for (int k = 1; k <= 3; k++) {
#pragma unroll
    for (int j = 0; j < 10; j++) {
      if (j + k < 11) {
        float gj   = (float)(j - 3) * 0.4f - 1.0f;
        float gj1  = (float)(j - 2) * 0.4f - 1.0f;
        float gjk  = (float)(j + k - 3) * 0.4f - 1.0f;
        float gjk1 = (float)(j + k - 2) * 0.4f - 1.0f;
        bs[j] = (x - gj) / (gjk - gj) * bs[j] + (gjk1 - x) / (gjk1 - gj1) * bs[j + 1];
      }
    }
  }
  size_t base = (size_t)n * ((size_t)infeat * 9);
  Xe[base + i] = f2bf(si);
  us8 u;
#pragma unroll
  for (int c = 0; c < 8; c++) u[c] = f2bf(bs[c]);
  *(us8*)(Xe + base + infeat + (size_t)i * 8) = u;
}

// ---------- KAN GEMM: C[M,N] = Xe[M,K](bf16) @ Wvirt[N,K]^T, W = [base | spline] f32 ----------
// Up to 3 projections along N (for fused qkv), each of width nper.

template <int BM, int BN>
__global__ __launch_bounds__(256)
void gemm_kan(const u16* __restrict__ A,
              const float* __restrict__ b0, const float* __restrict__ s0,
              const float* __restrict__ b1, const float* __restrict__ s1,
              const float* __restrict__ b2, const float* __restrict__ s2,
              int nper, int N, int K, int infeat, float* __restrict__ C) {
  constexpr int BK = 64;
  constexpr int FM = BM / 32, FN = BN / 32;
  __shared__ u16 As[BM * BK];
  __shared__ u16 Bs[BN * BK];
  const int m0 = blockIdx.x * BM;
  const int n0 = blockIdx.y * BN;
  const int t = threadIdx.x;
  const int lane = t & 63, wid = t >> 6;
  const int wm = (wid >> 1) * (BM / 2), wn = (wid & 1) * (BN / 2);
  const int proj = n0 / nper;                       // whole block in one projection (BN <= nper)
  const float* Wb = proj == 0 ? b0 : (proj == 1 ? b1 : b2);
  const float* Ws = proj == 0 ? s0 : (proj == 1 ? s1 : s2);
  const int onb = n0 - proj * nper;

  f32x4 acc[FM][FN];
#pragma unroll
  for (int i = 0; i < FM; i++)
#pragma unroll
    for (int j = 0; j < FN; j++) acc[i][j] = (f32x4){0.f, 0.f, 0.f, 0.f};

  const int frow = lane & 15;          // fragment row (A: M-row, B: N-row)
  const int kgrp = (lane >> 4) * 8;    // fragment k offset (8 contiguous bf16)

  for (int k0 = 0; k0 < K; k0 += BK) {
    // stage A (bf16 direct): BM x 64, 16B per thread-chunk
#pragma unroll
    for (int c = 0; c < BM / 32; c++) {
      int e = c * 256 + t;
      int r = e >> 3, sg = (e & 7) * 8;
      uint4 v = *(const uint4*)(A + (size_t)(m0 + r) * K + k0 + sg);
      *(uint4*)(&As[r * BK + sg]) = v;
    }
    // stage B (f32 -> bf16 convert): BN x 64
#pragma unroll
    for (int c = 0; c < BN / 32; c++) {
      int e = c * 256 + t;
      int r = e >> 3, sg = (e & 7) * 8;
      int kg = k0 + sg;
      int o = onb + r;
      const float* src = (kg < infeat) ? (Wb + (size_t)o * infeat + kg)
                                       : (Ws + (size_t)o * infeat * 8 + (kg - infeat));
      float4 f0 = *(const float4*)(src);
      float4 f1 = *(const float4*)(src + 4);
      us8 u;
      u[0] = f2bf(f0.x); u[1] = f2bf(f0.y); u[2] = f2bf(f0.z); u[3] = f2bf(f0.w);
      u[4] = f2bf(f1.x); u[5] = f2bf(f1.y); u[6] = f2bf(f1.z); u[7] = f2bf(f1.w);
      *(us8*)(&Bs[r * BK + sg]) = u;
    }
    __syncthreads();
#pragma unroll
    for (int kk = 0; kk < BK; kk += 32) {
      bf16x8 af[FM], bfr[FN];
#pragma unroll
      for (int i = 0; i < FM; i++)
        af[i] = *reinterpret_cast<const bf16x8*>(&As[(wm + i * 16 + frow) * BK + kk + kgrp]);
#pragma unroll
      for (int j = 0; j < FN; j++)
        bfr[j] = *reinterpret_cast<const bf16x8*>(&Bs[(wn + j * 16 + frow) * BK + kk + kgrp]);
#pragma unroll
      for (int i = 0; i < FM; i++)
#pragma unroll
        for (int j = 0; j < FN; j++)
          acc[i][j] = __builtin_amdgcn_mfma_f32_16x16x32_bf16(af[i], bfr[j], acc[i][j], 0, 0, 0);
    }
    __syncthreads();
  }
  // epilogue: C/D layout col = lane&15, row = (lane>>4)*4 + reg
  const int crow = (lane >> 4) * 4;
  const int ccol = lane & 15;
#pragma unroll
  for (int i = 0; i < FM; i++)
#pragma unroll
    for (int j = 0; j < FN; j++) {
      int row = m0 + wm + i * 16 + crow;
      int col = n0 + wn + j * 16 + ccol;
#pragma unroll
      for (int r = 0; r < 4; r++)
        C[(size_t)(row + r) * N + col] = acc[i][j][r];
    }
}

// ---------- attention: scores + softmax (block = 16 q-rows of one (b,h)) ----------

__global__ void attn_scores(const float* __restrict__ qkv, float* __restrict__ P) {
  int bh = blockIdx.x;              // 0..7
  int b = bh >> 2, h = bh & 3;
  int s0 = blockIdx.y * 16;
  int t = threadIdx.x;
  __shared__ float Qs[16][64];
  __shared__ float Ks[16][65];
  __shared__ float Ss[16][513];
  __shared__ float red[16][17];
#pragma unroll
  for (int c = 0; c < 4; c++) {
    int e = c * 256 + t, r = e >> 6, d = e & 63;
    Qs[r][d] = qkv[(size_t)(b * SEQ + s0 + r) * 768 + h * 64 + d];
  }
  int r = t >> 4, cc = t & 15;
  for (int kc = 0; kc < SEQ; kc += 16) {
    __syncthreads();
#pragma unroll
    for (int c = 0; c < 4; c++) {
      int e = c * 256 + t, rr = e >> 6, d = e & 63;
      Ks[rr][d] = qkv[(size_t)(b * SEQ + kc + rr) * 768 + 256 + h * 64 + d];
    }
    __syncthreads();
    float acc = 0.f;
#pragma unroll
    for (int d = 0; d < 64; d++) acc += Qs[r][d] * Ks[cc][d];
    Ss[r][kc + cc] = acc * 0.125f;
  }
  __syncthreads();
  float mx = -3.4e38f;
  for (int j = cc; j < SEQ; j += 16) mx = fmaxf(mx, Ss[r][j]);
  red[r][cc] = mx;
  __syncthreads();
  if (cc == 0) {
    float m = red[r][0];
#pragma unroll
    for (int j = 1; j < 16; j++) m = fmaxf(m, red[r][j]);
    red[r][16] = m;
  }
  __syncthreads();
  mx = red[r][16];
  float sm = 0.f;
  for (int j = cc; j < SEQ; j += 16) {
    float e = expf(Ss[r][j] - mx);
    Ss[r][j] = e;
    sm += e;
  }
  __syncthreads();
  red[r][cc] = sm;
  __syncthreads();
  if (cc == 0) {
    float s = 0.f;
#pragma unroll
    for (int j = 0; j < 16; j++) s += red[r][j];
    red[r][16] = s;
  }
  __syncthreads();
  float inv = 1.0f / red[r][16];
  float* prow = P + (size_t)(bh * SEQ + s0 + r) * SEQ;
  for (int j = cc; j < SEQ; j += 16) prow[j] = Ss[r][j] * inv;
}

// ---------- attention: ctx = P @ V ----------

__global__ void attn_ctx(const float* __restrict__ qkv, const float* __restrict__ P,
                         float* __restrict__ ctx) {
  int bh = blockIdx.x, b = bh >> 2, h = bh & 3;
  int s0 = blockIdx.y * 16;
  int t = threadIdx.x;
  __shared__ float Ps[16][513];
  __shared__ float Vs[32][65];
#pragma unroll
  for (int c = 0; c < 32; c++) {
    int e = c * 256 + t, r = e >> 9, j = e & 511;
    Ps[r][j] = P[(size_t)(bh * SEQ + s0 + r) * SEQ + j];
  }
  int r = t >> 4, dd = (t & 15) * 4;
  float a0 = 0, a1 = 0, a2 = 0, a3 = 0;
  for (int kc = 0; kc < SEQ; kc += 32) {
    __syncthreads();
#pragma unroll
    for (int c = 0; c < 8; c++) {
      int e = c * 256 + t, rr = e >> 6, d = e & 63;
      Vs[rr][d] = qkv[(size_t)(b * SEQ + kc + rr) * 768 + 512 + h * 64 + d];
    }
    __syncthreads();
#pragma unroll
    for (int kk = 0; kk < 32; kk++) {
      float p = Ps[r][kc + kk];
      a0 += p * Vs[kk][dd + 0];
      a1 += p * Vs[kk][dd + 1];
      a2 += p * Vs[kk][dd + 2];
      a3 += p * Vs[kk][dd + 3];
    }
  }
  float4 o4 = {a0, a1, a2, a3};
  *(float4*)&ctx[(size_t)(b * SEQ + s0 + r) * DIM + h * 64 + dd] = o4;
}

// ---------- launch ----------

extern "C" void kernel_launch(void* const* d_in, const int* in_sizes, int n_in,
                              void* d_out, int out_size, void* d_ws, size_t ws_size,
                              hipStream_t stream) {
  const int* ids = (const int*)d_in[0];
  const float* wemb = (const float*)d_in[1];
  const float* ttemb = (const float*)d_in[2];
  const float* pemb = (const float*)d_in[3];
  const float* elg = (const float*)d_in[4];
  const float* elb = (const float*)d_in[5];
  const float* qb = (const float*)d_in[6], *qs = (const float*)d_in[7];
  const float* kb = (const float*)d_in[8], *ks = (const float*)d_in[9];
  const float* vb = (const float*)d_in[10], *vs = (const float*)d_in[11];
  const float* ob = (const float*)d_in[12], *osp = (const float*)d_in[13];
  const float* f1b = (const float*)d_in[14], *f1s = (const float*)d_in[15];
  const float* f2b = (const float*)d_in[16], *f2s = (const float*)d_in[17];
  const float* l1g = (const float*)d_in[18], *l1b = (const float*)d_in[19];
  const float* l2g = (const float*)d_in[20], *l2b = (const float*)d_in[21];
  const float* hkb = (const float*)d_in[22], *hks = (const float*)d_in[23];
  const float* hob = (const float*)d_in[24], *hos = (const float*)d_in[25];
  float* out = (float*)d_out;

  char* w = (char*)d_ws;
  float* xbuf = (float*)(w);                       // 1 MB  [1024*256]
  float* tmp  = (float*)(w + (1 << 20));           // 1 MB  [1024*256]
  float* qkv  = (float*)(w + 2 * (1 << 20));       // 3 MB  [1024*768]
  float* ctx  = (float*)(w + 5 * (1 << 20));       // 1 MB  [1024*256]
  float* ff1  = (float*)(w + 6 * (1 << 20));       // 4 MB  [1024*1024]
  float* P    = (float*)(w + 10 * (1 << 20));      // 8 MB  [8*512*512]
  u16*   Xe   = (u16*)  (w + 18 * (1 << 20));      // 18.9 MB [1024*9216] bf16

  embed_ln<<<TOKENS, 256, 0, stream>>>(ids, wemb, ttemb, pemb, elg, elb, xbuf);

  for (int l = 0; l < 4; l++) {
    const float* qbl = qb + (size_t)l * 65536, *qsl = qs + (size_t)l * 524288;
    const float* kbl = kb + (size_t)l * 65536, *ksl = ks + (size_t)l * 524288;
    const float* vbl = vb + (size_t)l * 65536, *vsl = vs + (size_t)l * 524288;
    const float* obl = ob + (size_t)l * 65536, *osl = osp + (size_t)l * 524288;
    const float* f1bl = f1b + (size_t)l * 262144, *f1sl = f1s + (size_t)l * 2097152;
    const float* f2bl = f2b + (size_t)l * 262144, *f2sl = f2s + (size_t)l * 2097152;

    kan_expand<<<1024, 256, 0, stream>>>(xbuf, Xe, 8, 0);
    gemm_kan<64, 64><<<dim3(16, 12), 256, 0, stream>>>(
        Xe, qbl, qsl, kbl, ksl, vbl, vsl, 256, 768, 2304, 256, qkv);
    attn_scores<<<dim3(8, 32), 256, 0, stream>>>(qkv, P);
    attn_ctx<<<dim3(8, 32), 256, 0, stream>>>(qkv, P, ctx);
    kan_expand<<<1024, 256, 0, stream>>>(ctx, Xe, 8, 0);
    gemm_kan<64, 64><<<dim3(16, 4), 256, 0, stream>>>(
        Xe, obl, osl, obl, osl, obl, osl, 256, 256, 2304, 256, tmp);
    add_ln<<<TOKENS, 256, 0, stream>>>(tmp, xbuf, l1g + l * 256, l1b + l * 256, xbuf, 1e-5f, 0);
    kan_expand<<<1024, 256, 0, stream>>>(xbuf, Xe, 8, 0);
    gemm_kan<64, 64><<<dim3(16, 16), 256, 0, stream>>>(
        Xe, f1bl, f1sl, f1bl, f1sl, f1bl, f1sl, 1024, 1024, 2304, 256, ff1);
    kan_expand<<<4096, 256, 0, stream>>>(ff1, Xe, 10, 1);
    gemm_kan<64, 64><<<dim3(16, 4), 256, 0, stream>>>(
        Xe, f2bl, f2sl, f2bl, f2sl, f2bl, f2sl, 256, 256, 9216, 1024, tmp);
    add_ln<<<TOKENS, 256, 0, stream>>>(tmp, xbuf, l2g + l * 256, l2b + l * 256, xbuf, 1e-5f, 0);
  }

  // head: KAN -> gelu -> LN(no affine, eps 1e-12) -> KAN to vocab
  kan_expand<<<1024, 256, 0, stream>>>(xbuf, Xe, 8, 0);
  gemm_kan<64, 64><<<dim3(16, 4), 256, 0, stream>>>(
      Xe, hkb, hks, hkb, hks, hkb, hks, 256, 256, 2304, 256, tmp);
  add_ln<<<TOKENS, 256, 0, stream>>>(tmp, nullptr, nullptr, nullptr, ctx, 1e-12f, 1);
  kan_expand<<<1024, 256, 0, stream>>>(ctx, Xe, 8, 0);
  gemm_kan<128, 128><<<dim3(8, 250), 256, 0, stream>>>(
      Xe, hob, hos, hob, hos, hob, hos, 32000, 32000, 2304, 256, out);
}

// Round 2
// 1891.914 us; speedup vs baseline: 1.1877x; 1.1877x over previous
//
#include <hip/hip_runtime.h>
#include <math.h>

typedef unsigned short u16;
typedef unsigned int u32;
typedef __bf16 bf16x8 __attribute__((ext_vector_type(8)));
typedef float f32x4 __attribute__((ext_vector_type(4)));
typedef u16 us8 __attribute__((ext_vector_type(8)));

#define TOKENS 1024
#define DIM 256
#define SEQ 512

// ---------- helpers ----------

__device__ __forceinline__ u16 f2bf(float f) {
  // round-to-nearest-even f32 -> bf16 (values are finite here)
  u32 x = __float_as_uint(f);
  x += 0x7fffu + ((x >> 16) & 1u);
  return (u16)(x >> 16);
}

// 256-thread block sum (4 waves of 64)
__device__ __forceinline__ float block_sum_256(float v) {
  __shared__ float red[4];
  int t = threadIdx.x, lane = t & 63, wid = t >> 6;
#pragma unroll
  for (int o = 32; o > 0; o >>= 1) v += __shfl_down(v, o, 64);
  __syncthreads();               // protect red from a previous call's readers
  if (lane == 0) red[wid] = v;
  __syncthreads();
  return red[0] + red[1] + red[2] + red[3];
}

// ---------- embedding + LN (eps 1e-12) ----------

__global__ void embed_ln(const int* __restrict__ ids, const float* __restrict__ wemb,
                         const float* __restrict__ tt, const float* __restrict__ pe,
                         const float* __restrict__ g, const float* __restrict__ bta,
                         float* __restrict__ out) {
  int row = blockIdx.x, t = threadIdx.x;
  int id = ids[row];
  // faithful quirk: token-type row 1 and positional row 1 for every position
  float v = wemb[(size_t)id * DIM + t] + tt[DIM + t] + pe[DIM + t];
  float mu = block_sum_256(v) * (1.0f / 256.0f);
  float d = v - mu;
  float var = block_sum_256(d * d) * (1.0f / 256.0f);
  out[(size_t)row * DIM + t] = d * rsqrtf(var + 1e-12f) * g[t] + bta[t];
}

// ---------- (optional gelu) + residual + LN ----------

__global__ void add_ln(const float* __restrict__ a, const float* __restrict__ res,
                       const float* __restrict__ g, const float* __restrict__ bta,
                       float* __restrict__ out, float eps, int dogelu) {
  int row = blockIdx.x, t = threadIdx.x;
  float v = a[(size_t)row * DIM + t];
  if (dogelu) v = 0.5f * v * (1.0f + erff(v * 0.70710678118654752f));
  if (res) v += res[(size_t)row * DIM + t];
  float mu = block_sum_256(v) * (1.0f / 256.0f);
  float d = v - mu;
  float var = block_sum_256(d * d) * (1.0f / 256.0f);
  float y = d * rsqrtf(var + eps);
  if (g) y = y * g[t] + bta[t];
  out[(size_t)row * DIM + t] = y;
}

// ---------- KAN input expansion: x -> [silu(x) | B-spline bases(x)] in bf16 ----------

__global__ void kan_expand(const float* __restrict__ X, u16* __restrict__ Xe,
                           int shift, int dorelu) {
  int idx = blockIdx.x * 256 + threadIdx.x;
  int infeat = 1 << shift;
  int n = idx >> shift, i = idx & (infeat - 1);
  float x = X[idx];
  if (dorelu) x = fmaxf(x, 0.0f);
  float sig = 1.0f / (1.0f + expf(-x));
  float si = x * sig;
  // Cox-de Boor, uniform extended grid g[j] = (j-3)*0.4f - 1.0f, f32-faithful
  float bs[11];
#pragma unroll
  for (int j = 0; j < 11; j++) {
    float gj  = (float)(j - 3) * 0.4f - 1.0f;
    float gj1 = (float)(j - 2) * 0.4f - 1.0f;
    bs[j] = (x >= gj && x < gj1) ? 1.0f : 0.0f;
  }
#pragma unroll
  for (int k = 1; k <= 3; k++) {
#pragma unroll
    for (int j = 0; j < 10; j++) {
      if (j + k < 11) {
        float gj   = (float)(j - 3) * 0.4f - 1.0f;
        float gj1  = (float)(j - 2) * 0.4f - 1.0f;
        float gjk  = (float)(j + k - 3) * 0.4f - 1.0f;
        float gjk1 = (float)(j + k - 2) * 0.4f - 1.0f;
        bs[j] = (x - gj) / (gjk - gj) * bs[j] + (gjk1 - x) / (gjk1 - gj1) * bs[j + 1];
      }
    }
  }
  size_t base = (size_t)n * ((size_t)infeat * 9);
  Xe[base + i] = f2bf(si);
  us8 u;
#pragma unroll
  for (int c = 0; c < 8; c++) u[c] = f2bf(bs[c]);
  *(us8*)(Xe + base + infeat + (size_t)i * 8) = u;
}

// ---------- weight pack: [base | spline] f32 -> contiguous bf16 [rows x infeat*9] ----------

__global__ void pack_w(const float* __restrict__ base, const float* __restrict__ spl,
                       u16* __restrict__ dst, int shift, int nrows) {
  long idx = (long)blockIdx.x * 256 + threadIdx.x;
  if (idx >= ((long)nrows << shift)) return;
  int infeat = 1 << shift;
  long r = idx >> shift;
  int i = (int)(idx & (infeat - 1));
  int K = infeat * 9;
  dst[(size_t)r * K + i] = f2bf(base[idx]);
  const float* sp = spl + (size_t)idx * 8;
  float4 f0 = *(const float4*)sp;
  float4 f1v = *(const float4*)(sp + 4);
  us8 u;
  u[0] = f2bf(f0.x); u[1] = f2bf(f0.y); u[2] = f2bf(f0.z); u[3] = f2bf(f0.w);
  u[4] = f2bf(f1v.x); u[5] = f2bf(f1v.y); u[6] = f2bf(f1v.z); u[7] = f2bf(f1v.w);
  *(us8*)(dst + (size_t)r * K + infeat + (size_t)i * 8) = u;
}

// ---------- GEMM (packed bf16 weights): C[M,N] = A[M,K] @ W[N,K]^T ----------
// XCD-contiguous block remap + XOR chunk-swizzled LDS (conflict-free b128 reads).

template <int BM, int BN>
__global__ __launch_bounds__(256)
void gemm_b16(const u16* __restrict__ A,
              const u16* __restrict__ W0, const u16* __restrict__ W1, const u16* __restrict__ W2,
              int nper, int N, int K, float* __restrict__ C) {
  constexpr int BK = 64;
  constexpr int FM = BM / 32, FN = BN / 32;
  __shared__ u16 As[BM * BK];
  __shared__ u16 Bs[BN * BK];
  const int gx = gridDim.x;
  const int nwg = gx * gridDim.y;
  int g = blockIdx.y * gx + blockIdx.x;
  int lin = g;
  if ((nwg & 7) == 0) lin = (g & 7) * (nwg >> 3) + (g >> 3);   // XCD-contiguous
  const int m0 = (lin % gx) * BM;
  const int n0 = (lin / gx) * BN;
  const int t = threadIdx.x;
  const int lane = t & 63, wid = t >> 6;
  const int wm = (wid >> 1) * (BM / 2), wn = (wid & 1) * (BN / 2);
  const int proj = n0 / nper;
  const u16* W = proj == 0 ? W0 : (proj == 1 ? W1 : W2);
  const int onb = n0 - proj * nper;

  f32x4 acc[FM][FN];
#pragma unroll
  for (int i = 0; i < FM; i++)
#pragma unroll
    for (int j = 0; j < FN; j++) acc[i][j] = (f32x4){0.f, 0.f, 0.f, 0.f};

  const int frow = lane & 15;
  const int cgrp = lane >> 4;          // chunk group 0..3

  for (int k0 = 0; k0 < K; k0 += BK) {
#pragma unroll
    for (int c = 0; c < BM / 32; c++) {
      int e = c * 256 + t;
      int r = e >> 3, ch = e & 7;
      uint4 v = *(const uint4*)(A + (size_t)(m0 + r) * K + k0 + ch * 8);
      *(uint4*)(&As[r * BK + ((ch ^ (r & 7)) << 3)]) = v;
    }
#pragma unroll
    for (int c = 0; c < BN / 32; c++) {
      int e = c * 256 + t;
      int r = e >> 3, ch = e & 7;
      uint4 v = *(const uint4*)(W + (size_t)(onb + r) * K + k0 + ch * 8);
      *(uint4*)(&Bs[r * BK + ((ch ^ (r & 7)) << 3)]) = v;
    }
    __syncthreads();
#pragma unroll
    for (int half = 0; half < 2; half++) {
      const int ch = half * 4 + cgrp;
      bf16x8 af[FM], bfr[FN];
#pragma unroll
      for (int i = 0; i < FM; i++) {
        int ra = wm + i * 16 + frow;
        af[i] = *reinterpret_cast<const bf16x8*>(&As[ra * BK + ((ch ^ (ra & 7)) << 3)]);
      }
#pragma unroll
      for (int j = 0; j < FN; j++) {
        int rb = wn + j * 16 + frow;
        bfr[j] = *reinterpret_cast<const bf16x8*>(&Bs[rb * BK + ((ch ^ (rb & 7)) << 3)]);
      }
#pragma unroll
      for (int i = 0; i < FM; i++)
#pragma unroll
        for (int j = 0; j < FN; j++)
          acc[i][j] = __builtin_amdgcn_mfma_f32_16x16x32_bf16(af[i], bfr[j], acc[i][j], 0, 0, 0);
    }
    __syncthreads();
  }
  const int crow = (lane >> 4) * 4;
  const int ccol = lane & 15;
#pragma unroll
  for (int i = 0; i < FM; i++)
#pragma unroll
    for (int j = 0; j < FN; j++) {
      int row = m0 + wm + i * 16 + crow;
      int col = n0 + wn + j * 16 + ccol;
#pragma unroll
      for (int r = 0; r < 4; r++)
        C[(size_t)(row + r) * N + col] = acc[i][j][r];
    }
}

// ---------- fallback GEMM (f32 weights, converted in staging) ----------

template <int BM, int BN>
__global__ __launch_bounds__(256)
void gemm_f32(const u16* __restrict__ A,
              const float* __restrict__ b0, const float* __restrict__ s0,
              const float* __restrict__ b1, const float* __restrict__ s1,
              const float* __restrict__ b2, const float* __restrict__ s2,
              int nper, int N, int K, int infeat, float* __restrict__ C) {
  constexpr int BK = 64;
  constexpr int FM = BM / 32, FN = BN / 32;
  __shared__ u16 As[BM * BK];
  __shared__ u16 Bs[BN * BK];
  const int m0 = blockIdx.x * BM;
  const int n0 = blockIdx.y * BN;
  const int t = threadIdx.x;
  const int lane = t & 63, wid = t >> 6;
  const int wm = (wid >> 1) * (BM / 2), wn = (wid & 1) * (BN / 2);
  const int proj = n0 / nper;
  const float* Wb = proj == 0 ? b0 : (proj == 1 ? b1 : b2);
  const float* Ws = proj == 0 ? s0 : (proj == 1 ? s1 : s2);
  const int onb = n0 - proj * nper;

  f32x4 acc[FM][FN];
#pragma unroll
  for (int i = 0; i < FM; i++)
#pragma unroll
    for (int j = 0; j < FN; j++) acc[i][j] = (f32x4){0.f, 0.f, 0.f, 0.f};

  const int frow = lane & 15;
  const int kgrp = (lane >> 4) * 8;

  for (int k0 = 0; k0 < K; k0 += BK) {
#pragma unroll
    for (int c = 0; c < BM / 32; c++) {
      int e = c * 256 + t;
      int r = e >> 3, sg = (e & 7) * 8;
      uint4 v = *(const uint4*)(A + (size_t)(m0 + r) * K + k0 + sg);
      *(uint4*)(&As[r * BK + sg]) = v;
    }
#pragma unroll
    for (int c = 0; c < BN / 32; c++) {
      int e = c * 256 + t;
      int r = e >> 3, sg = (e & 7) * 8;
      int kg = k0 + sg;
      int o = onb + r;
      const float* src = (kg < infeat) ? (Wb + (size_t)o * infeat + kg)
                                       : (Ws + (size_t)o * infeat * 8 + (kg - infeat));
      float4 f0 = *(const float4*)(src);
      float4 f1 = *(const float4*)(src + 4);
      us8 u;
      u[0] = f2bf(f0.x); u[1] = f2bf(f0.y); u[2] = f2bf(f0.z); u[3] = f2bf(f0.w);
      u[4] = f2bf(f1.x); u[5] = f2bf(f1.y); u[6] = f2bf(f1.z); u[7] = f2bf(f1.w);
      *(us8*)(&Bs[r * BK + sg]) = u;
    }
    __syncthreads();
#pragma unroll
    for (int kk = 0; kk < BK; kk += 32) {
      bf16x8 af[FM], bfr[FN];
#pragma unroll
      for (int i = 0; i < FM; i++)
        af[i] = *reinterpret_cast<const bf16x8*>(&As[(wm + i * 16 + frow) * BK + kk + kgrp]);
#pragma unroll
      for (int j = 0; j < FN; j++)
        bfr[j] = *reinterpret_cast<const bf16x8*>(&Bs[(wn + j * 16 + frow) * BK + kk + kgrp]);
#pragma unroll
      for (int i = 0; i < FM; i++)
#pragma unroll
        for (int j = 0; j < FN; j++)
          acc[i][j] = __builtin_amdgcn_mfma_f32_16x16x32_bf16(af[i], bfr[j], acc[i][j], 0, 0, 0);
    }
    __syncthreads();
  }
  const int crow = (lane >> 4) * 4;
  const int ccol = lane & 15;
#pragma unroll
  for (int i = 0; i < FM; i++)
#pragma unroll
    for (int j = 0; j < FN; j++) {
      int row = m0 + wm + i * 16 + crow;
      int col = n0 + wn + j * 16 + ccol;
#pragma unroll
      for (int r = 0; r < 4; r++)
        C[(size_t)(row + r) * N + col] = acc[i][j][r];
    }
}

// ---------- attention: scores + softmax ----------

__global__ void attn_scores(const float* __restrict__ qkv, float* __restrict__ P) {
  int bh = blockIdx.x;
  int b = bh >> 2, h = bh & 3;
  int s0 = blockIdx.y * 16;
  int t = threadIdx.x;
  __shared__ float Qs[16][64];
  __shared__ float Ks[16][65];
  __shared__ float Ss[16][513];
  __shared__ float red[16][17];
#pragma unroll
  for (int c = 0; c < 4; c++) {
    int e = c * 256 + t, r = e >> 6, d = e & 63;
    Qs[r][d] = qkv[(size_t)(b * SEQ + s0 + r) * 768 + h * 64 + d];
  }
  int r = t >> 4, cc = t & 15;
  for (int kc = 0; kc < SEQ; kc += 16) {
    __syncthreads();
#pragma unroll
    for (int c = 0; c < 4; c++) {
      int e = c * 256 + t, rr = e >> 6, d = e & 63;
      Ks[rr][d] = qkv[(size_t)(b * SEQ + kc + rr) * 768 + 256 + h * 64 + d];
    }
    __syncthreads();
    float acc = 0.f;
#pragma unroll
    for (int d = 0; d < 64; d++) acc += Qs[r][d] * Ks[cc][d];
    Ss[r][kc + cc] = acc * 0.125f;
  }
  __syncthreads();
  float mx = -3.4e38f;
  for (int j = cc; j < SEQ; j += 16) mx = fmaxf(mx, Ss[r][j]);
  red[r][cc] = mx;
  __syncthreads();
  if (cc == 0) {
    float m = red[r][0];
#pragma unroll
    for (int j = 1; j < 16; j++) m = fmaxf(m, red[r][j]);
    red[r][16] = m;
  }
  __syncthreads();
  mx = red[r][16];
  float sm = 0.f;
  for (int j = cc; j < SEQ; j += 16) {
    float e = expf(Ss[r][j] - mx);
    Ss[r][j] = e;
    sm += e;
  }
  __syncthreads();
  red[r][cc] = sm;
  __syncthreads();
  if (cc == 0) {
    float s = 0.f;
#pragma unroll
    for (int j = 0; j < 16; j++) s += red[r][j];
    red[r][16] = s;
  }
  __syncthreads();
  float inv = 1.0f / red[r][16];
  float* prow = P + (size_t)(bh * SEQ + s0 + r) * SEQ;
  for (int j = cc; j < SEQ; j += 16) prow[j] = Ss[r][j] * inv;
}

// ---------- attention: ctx = P @ V ----------

__global__ void attn_ctx(const float* __restrict__ qkv, const float* __restrict__ P,
                         float* __restrict__ ctx) {
  int bh = blockIdx.x, b = bh >> 2, h = bh & 3;
  int s0 = blockIdx.y * 16;
  int t = threadIdx.x;
  __shared__ float Ps[16][513];
  __shared__ float Vs[32][65];
#pragma unroll
  for (int c = 0; c < 32; c++) {
    int e = c * 256 + t, r = e >> 9, j = e & 511;
    Ps[r][j] = P[(size_t)(bh * SEQ + s0 + r) * SEQ + j];
  }
  int r = t >> 4, dd = (t & 15) * 4;
  float a0 = 0, a1 = 0, a2 = 0, a3 = 0;
  for (int kc = 0; kc < SEQ; kc += 32) {
    __syncthreads();
#pragma unroll
    for (int c = 0; c < 8; c++) {
      int e = c * 256 + t, rr = e >> 6, d = e & 63;
      Vs[rr][d] = qkv[(size_t)(b * SEQ + kc + rr) * 768 + 512 + h * 64 + d];
    }
    __syncthreads();
#pragma unroll
    for (int kk = 0; kk < 32; kk++) {
      float p = Ps[r][kc + kk];
      a0 += p * Vs[kk][dd + 0];
      a1 += p * Vs[kk][dd + 1];
      a2 += p * Vs[kk][dd + 2];
      a3 += p * Vs[kk][dd + 3];
    }
  }
  float4 o4 = {a0, a1, a2, a3};
  *(float4*)&ctx[(size_t)(b * SEQ + s0 + r) * DIM + h * 64 + dd] = o4;
}

// ---------- launch ----------

extern "C" void kernel_launch(void* const* d_in, const int* in_sizes, int n_in,
                              void* d_out, int out_size, void* d_ws, size_t ws_size,
                              hipStream_t stream) {
  const int* ids = (const int*)d_in[0];
  const float* wemb = (const float*)d_in[1];
  const float* ttemb = (const float*)d_in[2];
  const float* pemb = (const float*)d_in[3];
  const float* elg = (const float*)d_in[4];
  const float* elb = (const float*)d_in[5];
  const float* qb = (const float*)d_in[6], *qs = (const float*)d_in[7];
  const float* kb = (const float*)d_in[8], *ks = (const float*)d_in[9];
  const float* vb = (const float*)d_in[10], *vs = (const float*)d_in[11];
  const float* ob = (const float*)d_in[12], *osp = (const float*)d_in[13];
  const float* f1b = (const float*)d_in[14], *f1s = (const float*)d_in[15];
  const float* f2b = (const float*)d_in[16], *f2s = (const float*)d_in[17];
  const float* l1g = (const float*)d_in[18], *l1b = (const float*)d_in[19];
  const float* l2g = (const float*)d_in[20], *l2b = (const float*)d_in[21];
  const float* hkb = (const float*)d_in[22], *hks = (const float*)d_in[23];
  const float* hob = (const float*)d_in[24], *hos = (const float*)d_in[25];
  float* out = (float*)d_out;

  char* w = (char*)d_ws;
  float* xbuf = (float*)(w);                       // 1 MB  [1024*256]
  float* tmp  = (float*)(w + (1 << 20));           // 1 MB
  float* qkv  = (float*)(w + 2 * (1 << 20));       // 3 MB  [1024*768]
  float* ctx  = (float*)(w + 5 * (1 << 20));       // 1 MB
  float* ff1  = (float*)(w + 6 * (1 << 20));       // 4 MB  [1024*1024]
  float* P    = (float*)(w + 10 * (1 << 20));      // 8 MB  [8*512*512]
  u16*   Xe   = (u16*)  (w + 18 * (1 << 20));      // 18.9 MB [1024*9216]
  u16*   Wc   = (u16*)  (w + 37 * (1 << 20));      // packed bf16 weights (196 MB)

  // packed-weight element offsets within Wc
  const size_t oq = 0, okk = 2359296, ov = 4718592, oo = 7077888;
  const size_t of1 = 9437184, of2 = 18874368, ohk = 28311552, oho = 28901376;
  const size_t wc_end = oho + 73728000;            // 102,629,376 elems
  const size_t NEED = 37 * (size_t)(1 << 20) + wc_end * 2;
  const bool packed = ws_size >= NEED;

  if (packed) {
    pack_w<<<(1024 * 256 + 255) / 256, 256, 0, stream>>>(qb, qs, Wc + oq, 8, 1024);
    pack_w<<<(1024 * 256 + 255) / 256, 256, 0, stream>>>(kb, ks, Wc + okk, 8, 1024);
    pack_w<<<(1024 * 256 + 255) / 256, 256, 0, stream>>>(vb, vs, Wc + ov, 8, 1024);
    pack_w<<<(1024 * 256 + 255) / 256, 256, 0, stream>>>(ob, osp, Wc + oo, 8, 1024);
    pack_w<<<(4096 * 256 + 255) / 256, 256, 0, stream>>>(f1b, f1s, Wc + of1, 8, 4096);
    pack_w<<<(1024 * 1024 + 255) / 256, 256, 0, stream>>>(f2b, f2s, Wc + of2, 10, 1024);
    pack_w<<<(256 * 256 + 255) / 256, 256, 0, stream>>>(hkb, hks, Wc + ohk, 8, 256);
    pack_w<<<(32000 * 256 + 255) / 256, 256, 0, stream>>>(hob, hos, Wc + oho, 8, 32000);
  }

  embed_ln<<<TOKENS, 256, 0, stream>>>(ids, wemb, ttemb, pemb, elg, elb, xbuf);

  for (int l = 0; l < 4; l++) {
    const size_t wl = (size_t)l * 589824, fl = (size_t)l * 2359296;
    const float* qbl = qb + (size_t)l * 65536, *qsl = qs + (size_t)l * 524288;
    const float* kbl = kb + (size_t)l * 65536, *ksl = ks + (size_t)l * 524288;
    const float* vbl = vb + (size_t)l * 65536, *vsl = vs + (size_t)l * 524288;
    const float* obl = ob + (size_t)l * 65536, *osl = osp + (size_t)l * 524288;
    const float* f1bl = f1b + (size_t)l * 262144, *f1sl = f1s + (size_t)l * 2097152;
    const float* f2bl = f2b + (size_t)l * 262144, *f2sl = f2s + (size_t)l * 2097152;

    kan_expand<<<1024, 256, 0, stream>>>(xbuf, Xe, 8, 0);
    if (packed)
      gemm_b16<64, 64><<<dim3(16, 12), 256, 0, stream>>>(
          Xe, Wc + oq + wl, Wc + okk + wl, Wc + ov + wl, 256, 768, 2304, qkv);
    else
      gemm_f32<64, 64><<<dim3(16, 12), 256, 0, stream>>>(
          Xe, qbl, qsl, kbl, ksl, vbl, vsl, 256, 768, 2304, 256, qkv);
    attn_scores<<<dim3(8, 32), 256, 0, stream>>>(qkv, P);
    attn_ctx<<<dim3(8, 32), 256, 0, stream>>>(qkv, P, ctx);
    kan_expand<<<1024, 256, 0, stream>>>(ctx, Xe, 8, 0);
    if (packed)
      gemm_b16<64, 64><<<dim3(16, 4), 256, 0, stream>>>(
          Xe, Wc + oo + wl, Wc + oo + wl, Wc + oo + wl, 256, 256, 2304, tmp);
    else
      gemm_f32<64, 64><<<dim3(16, 4), 256, 0, stream>>>(
          Xe, obl, osl, obl, osl, obl, osl, 256, 256, 2304, 256, tmp);
    add_ln<<<TOKENS, 256, 0, stream>>>(tmp, xbuf, l1g + l * 256, l1b + l * 256, xbuf, 1e-5f, 0);
    kan_expand<<<1024, 256, 0, stream>>>(xbuf, Xe, 8, 0);
    if (packed)
      gemm_b16<64, 64><<<dim3(16, 16), 256, 0, stream>>>(
          Xe, Wc + of1 + fl, Wc + of1 + fl, Wc + of1 + fl, 1024, 1024, 2304, ff1);
    else
      gemm_f32<64, 64><<<dim3(16, 16), 256, 0, stream>>>(
          Xe, f1bl, f1sl, f1bl, f1sl, f1bl, f1sl, 1024, 1024, 2304, 256, ff1);
    kan_expand<<<4096, 256, 0, stream>>>(ff1, Xe, 10, 1);
    if (packed)
      gemm_b16<64, 64><<<dim3(16, 4), 256, 0, stream>>>(
          Xe, Wc + of2 + fl, Wc + of2 + fl, Wc + of2 + fl, 256, 256, 9216, tmp);
    else
      gemm_f32<64, 64><<<dim3(16, 4), 256, 0, stream>>>(
          Xe, f2bl, f2sl, f2bl, f2sl, f2bl, f2sl, 256, 256, 9216, 1024, tmp);
    add_ln<<<TOKENS, 256, 0, stream>>>(tmp, xbuf, l2g + l * 256, l2b + l * 256, xbuf, 1e-5f, 0);
  }

  // head: KAN -> gelu -> LN(no affine, eps 1e-12) -> KAN to vocab
  kan_expand<<<1024, 256, 0, stream>>>(xbuf, Xe, 8, 0);
  if (packed)
    gemm_b16<64, 64><<<dim3(16, 4), 256, 0, stream>>>(
        Xe, Wc + ohk, Wc + ohk, Wc + ohk, 256, 256, 2304, tmp);
  else
    gemm_f32<64, 64><<<dim3(16, 4), 256, 0, stream>>>(
        Xe, hkb, hks, hkb, hks, hkb, hks, 256, 256, 2304, 256, tmp);
  add_ln<<<TOKENS, 256, 0, stream>>>(tmp, nullptr, nullptr, nullptr, ctx, 1e-12f, 1);
  kan_expand<<<1024, 256, 0, stream>>>(ctx, Xe, 8, 0);
  if (packed)
    gemm_b16<128, 128><<<dim3(8, 250), 256, 0, stream>>>(
        Xe, Wc + oho, Wc + oho, Wc + oho, 32000, 32000, 2304, out);
  else
    gemm_f32<128, 128><<<dim3(8, 250), 256, 0, stream>>>(
        Xe, hob, hos, hob, hos, hob, hos, 32000, 32000, 2304, 256, out);
}